// Round 10
// baseline (172.355 us; speedup 1.0000x reference)
//
#include <hip/hip_runtime.h>
#include <math.h>

typedef _Float16 f16;
typedef f16 f16x2 __attribute__((ext_vector_type(2)));

__device__ __forceinline__ float dot2acc(f16x2 a, f16x2 b, float c){
#if __has_builtin(__builtin_amdgcn_fdot2)
  return __builtin_amdgcn_fdot2(a, b, c, false);
#else
  return c + (float)a[0]*(float)b[0] + (float)a[1]*(float)b[1];
#endif
}

// ---------------- conv1: 12->3, 3x3, s1, SAME. thread = 4 cols x 1 row x 3 oc ----------------
// grid (40,64): 2560 blocks -> ~8 waves/SIMD; TLP is the lever (R4->R5 trend).
__global__ __launch_bounds__(256) void k_conv1(const float* __restrict__ img,
    const float* __restrict__ cw, const float* __restrict__ cb,
    float* __restrict__ c1){
  int b = blockIdx.y, ty = blockIdx.x;     // ty 0..39 -> 5 output rows
  int t = threadIdx.x;
  if (t >= 250) return;
  int cg = t % 50, r = t / 50;             // r 0..4
  int x0 = cg*4;
  int y = ty*5 + r;
  const float* ib = img + (size_t)b*480000 + x0;
  float* ob = c1 + (size_t)b*120000;

  float acc[3][4];
  #pragma unroll
  for (int oc=0;oc<3;++oc){
    float bz = cb[oc];
    #pragma unroll
    for (int c=0;c<4;++c) acc[oc][c] = bz;
  }
  bool xl = (cg>0), xr = (cg<49);
  for (int ci=0; ci<12; ++ci){
    const float* p = ib + ci*40000;
    float vr[3][6];
    #pragma unroll
    for (int rr=0; rr<3; ++rr){
      int iy = y - 1 + rr;
      bool rok = (unsigned)iy < 200u;
      const float* rp = p + iy*200;
      float4 m = rok ? *(const float4*)rp : make_float4(0.f,0.f,0.f,0.f);
      vr[rr][0] = (rok && xl) ? rp[-1] : 0.f;
      vr[rr][1] = m.x; vr[rr][2] = m.y; vr[rr][3] = m.z; vr[rr][4] = m.w;
      vr[rr][5] = (rok && xr) ? rp[4] : 0.f;
    }
    #pragma unroll
    for (int oc=0;oc<3;++oc){
      const float* wp = cw + oc*108 + ci*9;
      float w00=wp[0], w01=wp[1], w02=wp[2],
            w10=wp[3], w11=wp[4], w12=wp[5],
            w20=wp[6], w21=wp[7], w22=wp[8];
      #pragma unroll
      for (int c=0;c<4;++c){
        float s = acc[oc][c];
        s = fmaf(vr[0][c+0], w00, s); s = fmaf(vr[0][c+1], w01, s); s = fmaf(vr[0][c+2], w02, s);
        s = fmaf(vr[1][c+0], w10, s); s = fmaf(vr[1][c+1], w11, s); s = fmaf(vr[1][c+2], w12, s);
        s = fmaf(vr[2][c+0], w20, s); s = fmaf(vr[2][c+1], w21, s); s = fmaf(vr[2][c+2], w22, s);
        acc[oc][c] = s;
      }
    }
  }
  #pragma unroll
  for (int oc=0;oc<3;++oc)
    *(float4*)(ob + oc*40000 + y*200 + x0) =
      make_float4(acc[oc][0], acc[oc][1], acc[oc][2], acc[oc][3]);
}

// ------------- conv2: 3->32, 3x3, s2, SAME + relu + partial mean. thread = 2 cols x 1 row ------
__global__ __launch_bounds__(256) void k_conv2(const float* __restrict__ c1,
    const float* __restrict__ w2, const float* __restrict__ b2,
    float* __restrict__ part){
  int b = blockIdx.y, ty = blockIdx.x;     // ty 0..19 -> 5 output rows
  int t = threadIdx.x;
  float acc[32];
  #pragma unroll
  for (int co=0;co<32;++co) acc[co]=0.f;
  if (t < 250){
    int oy  = ty*5 + t/50;
    int ox0 = (t%50)*2;
    const float* cbs = c1 + (size_t)b*120000;
    bool xl = (ox0>0);
    float vr[3][3][5];
    #pragma unroll
    for (int ci=0;ci<3;++ci){
      #pragma unroll
      for (int ky=0;ky<3;++ky){
        int iy = 2*oy + ky - 1;
        bool rok = (iy >= 0);              // iy <= 199 always
        const float* rp = cbs + ci*40000 + iy*200 + 2*ox0;
        float4 m = rok ? *(const float4*)rp : make_float4(0.f,0.f,0.f,0.f);
        vr[ci][ky][0] = (rok && xl) ? rp[-1] : 0.f;
        vr[ci][ky][1] = m.x; vr[ci][ky][2] = m.y; vr[ci][ky][3] = m.z; vr[ci][ky][4] = m.w;
      }
    }
    #pragma unroll
    for (int c=0;c<2;++c){
      #pragma unroll
      for (int co=0;co<32;++co){
        float s = b2[co];
        #pragma unroll
        for (int ci=0;ci<3;++ci)
          #pragma unroll
          for (int ky=0;ky<3;++ky)
            #pragma unroll
            for (int kx=0;kx<3;++kx)
              s = fmaf(vr[ci][ky][2*c+kx], w2[co*27+ci*9+ky*3+kx], s);
        acc[co] += fmaxf(s, 0.f);
      }
    }
  }
  int lane = t&63, wv = t>>6;
  __shared__ float wred[4][32];
  #pragma unroll
  for (int co=0;co<32;++co){
    float s = acc[co];
    #pragma unroll
    for (int off=32; off; off>>=1) s += __shfl_down(s, off, 64);
    if (lane==0) wred[wv][co] = s;
  }
  __syncthreads();
  if (t < 32){
    float s = wred[0][t]+wred[1][t]+wred[2][t]+wred[3][t];
    part[(b*20+ty)*32 + t] = s;
  }
}

// ------------- LSTM with inline fc (const4) prologue; 1 block per batch -------------
__global__ __launch_bounds__(256) void k_lstm(
    const float* __restrict__ hist_pts, const float* __restrict__ hist_step,
    const float* __restrict__ emb_w, const float* __restrict__ emb_b,
    const float* __restrict__ h0, const float* __restrict__ c0,
    const float* __restrict__ w_ih, const float* __restrict__ w_hh,
    const float* __restrict__ b_ih, const float* __restrict__ b_hh,
    const float* __restrict__ out_w, const float* __restrict__ out_b,
    const float* __restrict__ part, const float* __restrict__ fcw,
    const float* __restrict__ fcb, float* __restrict__ traj){
  int b = blockIdx.x; int t = threadIdx.x; int lane = t&63, wv = t>>6;

  // ---- inline fc: const4 = (mean-pooled z @ fcw^T + fcb) @ out_w[:,128:]^T + out_b ----
  __shared__ float zfc[32];
  __shared__ float wredfc[4][4];
  if (t < 32){
    float s = 0.f;
    #pragma unroll
    for (int p=0;p<20;++p) s += part[(b*20+p)*32 + t];
    zfc[t] = s * (1.f/10000.f);
  }
  __syncthreads();
  {
    float cp0=0.f, cp1=0.f, cp2=0.f, cp3=0.f;
    for (int o = t; o < 1000; o += 256){
      float s = fcb[o];
      #pragma unroll
      for (int k=0;k<32;++k) s = fmaf(fcw[o*32+k], zfc[k], s);
      cp0 = fmaf(s, out_w[0*1128+128+o], cp0);
      cp1 = fmaf(s, out_w[1*1128+128+o], cp1);
      cp2 = fmaf(s, out_w[2*1128+128+o], cp2);
      cp3 = fmaf(s, out_w[3*1128+128+o], cp3);
    }
    #pragma unroll
    for (int off=32; off; off>>=1){
      cp0 += __shfl_down(cp0, off, 64);
      cp1 += __shfl_down(cp1, off, 64);
      cp2 += __shfl_down(cp2, off, 64);
      cp3 += __shfl_down(cp3, off, 64);
    }
    if (lane==0){ wredfc[wv][0]=cp0; wredfc[wv][1]=cp1; wredfc[wv][2]=cp2; wredfc[wv][3]=cp3; }
  }
  __syncthreads();
  float cst = 0.f;
  if (t < 4) cst = out_b[t] + wredfc[0][t]+wredfc[1][t]+wredfc[2][t]+wredfc[3][t];

  // ---- LSTM ----
  int u  = (t<128) ? t       : t-128;
  int j1 = (t<128) ? t       : 128+u;   // i_u  or f_u
  int j2 = (t<128) ? 256+t   : 384+u;   // g_u  or o_u

  f16x2 w1[96], w2[96];
  {
    const float2* r1 = (const float2*)(w_ih + j1*64);
    const float2* r2 = (const float2*)(w_ih + j2*64);
    #pragma unroll
    for (int p=0;p<32;++p){
      float2 a = r1[p], c = r2[p];
      w1[p] = f16x2{(f16)a.x, (f16)a.y};
      w2[p] = f16x2{(f16)c.x, (f16)c.y};
    }
    const float2* q1 = (const float2*)(w_hh + j1*128);
    const float2* q2 = (const float2*)(w_hh + j2*128);
    #pragma unroll
    for (int p=0;p<64;++p){
      float2 a = q1[p], c = q2[p];
      w1[32+p] = f16x2{(f16)a.x, (f16)a.y};
      w2[32+p] = f16x2{(f16)c.x, (f16)c.y};
    }
  }
  float bias1 = b_ih[j1] + b_hh[j1];
  float bias2 = b_ih[j2] + b_hh[j2];

  __shared__ f16x2 xl[96];
  __shared__ float e_lds[64], h_lds[128], a_lds[128];
  __shared__ float step_lds[4], wred4[4];

  float c_reg = (t>=128) ? c0[u] : 0.f;
  if (t < 128) h_lds[t] = h0[t];

  auto cell = [&](){
    __syncthreads();
    if (t < 32)      xl[t]    = f16x2{(f16)e_lds[2*t],        (f16)e_lds[2*t+1]};
    else if (t < 96){ int p=t-32; xl[t] = f16x2{(f16)h_lds[2*p], (f16)h_lds[2*p+1]}; }
    __syncthreads();
    float acc1 = bias1, acc2 = bias2;
    #pragma unroll
    for (int cc=0; cc<12; ++cc){
      f16x2 xv[8];
      #pragma unroll
      for (int q=0;q<8;++q) xv[q] = xl[cc*8+q];
      #pragma unroll
      for (int q=0;q<8;++q){
        acc1 = dot2acc(w1[cc*8+q], xv[q], acc1);
        acc2 = dot2acc(w2[cc*8+q], xv[q], acc2);
      }
    }
    if (t < 128){
      float ig = 1.f/(1.f+expf(-acc1));
      float gg = tanhf(acc2);
      a_lds[t] = ig*gg;
    }
    __syncthreads();
    if (t >= 128){
      float ff = 1.f/(1.f+expf(-acc1));
      float oo = 1.f/(1.f+expf(-acc2));
      c_reg = ff*c_reg + a_lds[u];
      h_lds[u] = oo * tanhf(c_reg);
    }
  };

  for (int s=1; s<10; ++s){
    if (t < 64){
      const float* hp = hist_step + (size_t)(b*10+s)*4;
      float e = emb_b[t]
              + emb_w[t*4+0]*hp[0] + emb_w[t*4+1]*hp[1]
              + emb_w[t*4+2]*hp[2] + emb_w[t*4+3]*hp[3];
      e_lds[t] = fmaxf(e, 0.f);
    }
    cell();
  }

  float pose = (t<4) ? hist_pts[(size_t)(b*10+9)*4 + t] : 0.f;
  for (int it=0; it<10; ++it){
    __syncthreads();
    {
      const float* owr = out_w + wv*1128;
      float p_ = owr[2*lane]*h_lds[2*lane] + owr[2*lane+1]*h_lds[2*lane+1];
      #pragma unroll
      for (int off=32; off; off>>=1) p_ += __shfl_down(p_, off, 64);
      if (lane==0) wred4[wv] = p_;
    }
    __syncthreads();
    if (t < 4){
      float st = wred4[t] + cst;
      pose += st;
      traj[(size_t)(b*10+it)*4 + t] = pose;
      step_lds[t] = st;
    }
    __syncthreads();
    if (it < 9){
      if (t < 64){
        float e = emb_b[t]
                + emb_w[t*4+0]*step_lds[0] + emb_w[t*4+1]*step_lds[1]
                + emb_w[t*4+2]*step_lds[2] + emb_w[t*4+3]*step_lds[3];
        e_lds[t] = fmaxf(e, 0.f);
      }
      cell();
    }
  }
}

// ------------- rasterizer: max of 3 isotropic gaussians = exp(-min d^2 / (2 s^2)) -------------
__global__ __launch_bounds__(256) void k_raster(const float* __restrict__ traj,
    const float* __restrict__ ego, float* __restrict__ boxes){
  int img = blockIdx.y;
  int b = img / 10;
  __shared__ float ctr[6];
  if (threadIdx.x == 0){
    float x  = traj[img*4+0];
    float y  = traj[img*4+1];
    float hd = traj[img*4+2];
    float eg = ego[b];
    float ho = 1.5707963267948966f - eg;
    float sho, cho; __sincosf(ho, &sho, &cho);
    float pxc = 100.f + (x*cho - y*sho)*10.f;
    float pyc = 160.f - (x*sho + y*cho)*10.f;
    float bh  = -hd - eg;
    float sbh, cbh; __sincosf(bh, &sbh, &cbh);
    const float CSH = 14.235f;
    const float FSH = 28.47f;
    ctr[0] = pxc;             ctr[1] = pyc;
    ctr[2] = pxc + CSH*cbh;   ctr[3] = pyc - CSH*sbh;
    ctr[4] = pxc + FSH*cbh;   ctr[5] = pyc - FSH*sbh;
  }
  __syncthreads();
  int f4 = blockIdx.x*256 + threadIdx.x;
  if (f4 >= 10000) return;
  int p0 = f4*4;
  int i = p0 / 200;
  int j = p0 % 200;
  float fi = (float)i, fj = (float)j;
  float c0x=ctr[0], c0y=ctr[1], c1x=ctr[2], c1y=ctr[3], c2x=ctr[4], c2y=ctr[5];
  float dx0 = fi-c0x, dx1 = fi-c1x, dx2 = fi-c2x;
  float A0 = dx0*dx0, A1 = dx1*dx1, A2 = dx2*dx2;
  const float GA = 0.15432098765432098f;
  float r[4];
  #pragma unroll
  for (int l=0;l<4;++l){
    float dj = fj + (float)l;
    float dy0 = dj-c0y, dy1 = dj-c1y, dy2 = dj-c2y;
    float d0 = fmaf(dy0,dy0,A0);
    float d1 = fmaf(dy1,dy1,A1);
    float d2 = fmaf(dy2,dy2,A2);
    float m = fminf(d0, fminf(d1,d2));
    r[l] = __expf(-m*GA);
  }
  *(float4*)(boxes + (size_t)img*40000 + p0) = make_float4(r[0],r[1],r[2],r[3]);
}

extern "C" void kernel_launch(void* const* d_in, const int* in_sizes, int n_in,
                              void* d_out, int out_size, void* d_ws, size_t ws_size,
                              hipStream_t stream) {
  (void)in_sizes; (void)n_in; (void)d_ws; (void)ws_size; (void)out_size;
  const float* img = (const float*)d_in[0];
  const float* hp  = (const float*)d_in[1];
  const float* hps = (const float*)d_in[2];
  const float* ego = (const float*)d_in[3];
  const float* cw  = (const float*)d_in[4];
  const float* cb  = (const float*)d_in[5];
  const float* c2w = (const float*)d_in[6];
  const float* c2b = (const float*)d_in[7];
  const float* fcw = (const float*)d_in[8];
  const float* fcb = (const float*)d_in[9];
  const float* ew  = (const float*)d_in[10];
  const float* eb  = (const float*)d_in[11];
  const float* h0  = (const float*)d_in[12];
  const float* c0  = (const float*)d_in[13];
  const float* wih = (const float*)d_in[14];
  const float* whh = (const float*)d_in[15];
  const float* bih = (const float*)d_in[16];
  const float* bhh = (const float*)d_in[17];
  const float* ow  = (const float*)d_in[18];
  const float* ob  = (const float*)d_in[19];

  float* out  = (float*)d_out;
  float* traj = out;                 // (64,10,4)
  float* S    = out + 2560;          // boxes region doubles as scratch until k_raster
  float* part = S;                   // 64*20*32 floats
  float* c1   = S + 50000;           // 64*3*200*200 = 7.68M floats (16B-aligned)

  hipLaunchKernelGGL(k_conv1, dim3(40, 64), dim3(256), 0, stream, img, cw, cb, c1);
  hipLaunchKernelGGL(k_conv2, dim3(20, 64), dim3(256), 0, stream, c1, c2w, c2b, part);
  hipLaunchKernelGGL(k_lstm,  dim3(64),     dim3(256), 0, stream,
                     hp, hps, ew, eb, h0, c0, wih, whh, bih, bhh, ow, ob, part, fcw, fcb, traj);
  hipLaunchKernelGGL(k_raster, dim3(40, 640), dim3(256), 0, stream, traj, ego, S);
}

// Round 11
// 133.068 us; speedup vs baseline: 1.2952x; 1.2952x over previous
//
#include <hip/hip_runtime.h>
#include <math.h>

typedef _Float16 f16;
typedef f16 f16x2 __attribute__((ext_vector_type(2)));

__device__ __forceinline__ float dot2acc(f16x2 a, f16x2 b, float c){
#if __has_builtin(__builtin_amdgcn_fdot2)
  return __builtin_amdgcn_fdot2(a, b, c, false);
#else
  return c + (float)a[0]*(float)b[0] + (float)a[1]*(float)b[1];
#endif
}

// ---------------- conv1: 12->3, 3x3, s1, SAME ----------------
// Block = (b, 10-row band). Per channel: stage 12 contiguous rows (9.6KB) into LDS
// via global_load_lds (double-buffered, prefetch ci+1 during compute ci).
// Compute: thread = 4 cols x 2 rows x 3 oc, all reads from LDS.
__global__ __launch_bounds__(256) void k_conv1(const float* __restrict__ img,
    const float* __restrict__ cw, const float* __restrict__ cb,
    float* __restrict__ c1){
  int b = blockIdx.y, ty = blockIdx.x;     // ty 0..19 -> rows [10ty,10ty+10)
  int t = threadIdx.x, lane = t & 63, wv = t >> 6;
  int y0 = ty*10;
  int cg = t % 50, rt = t / 50;            // compute mapping (t<250)

  __shared__ __align__(16) float sbuf[2][2404];   // 12 rows x 200 (+pad)

  // --- staging precompute: chunks k = wv+4j (k<10), element e = k*64+lane < 600 float4s ---
  int goff[3]; bool gact[3];
  #pragma unroll
  for (int j=0;j<3;++j){
    int k = wv + 4*j;
    int e = k*64 + lane;
    gact[j] = (k < 10) && (e < 600);
    int r = e/50, c4 = e - 50*r;           // local row 0..11, col4 0..49
    int gy = y0 - 1 + r; gy = gy < 0 ? 0 : (gy > 199 ? 199 : gy);  // clamp (masked at compute)
    goff[j] = gy*200 + c4*4;
  }
  const float* cbase0 = img + (size_t)b*480000;

  bool rok[4];
  #pragma unroll
  for (int rr=0; rr<4; ++rr){
    int gy = y0 + rt*2 - 1 + rr;
    rok[rr] = (unsigned)gy < 200u;
  }
  bool xl = (cg>0), xr = (cg<49);

  float acc[3][2][4];
  #pragma unroll
  for (int oc=0;oc<3;++oc){
    float bz = cb[oc];
    #pragma unroll
    for (int jj=0;jj<2;++jj)
      #pragma unroll
      for (int c=0;c<4;++c) acc[oc][jj][c] = bz;
  }

  auto STAGE = [&](int buf, int ci){
    const float* cp = cbase0 + ci*40000;
    #pragma unroll
    for (int j=0;j<3;++j){
      if (gact[j]){
        int k = wv + 4*j;
        const float* g = cp + goff[j];
#if __has_builtin(__builtin_amdgcn_global_load_lds)
        __builtin_amdgcn_global_load_lds(
            (const __attribute__((address_space(1))) void*)g,
            (__attribute__((address_space(3))) void*)&sbuf[buf][k*256], 16, 0, 0);
#else
        *(float4*)&sbuf[buf][(k*64 + lane)*4] = *(const float4*)g;
#endif
      }
    }
  };

  STAGE(0, 0);
  __syncthreads();
  for (int ci=0; ci<12; ++ci){
    int cur = ci & 1;
    if (ci < 11) STAGE(cur^1, ci+1);
    if (t < 250){
      float vr[4][6];
      #pragma unroll
      for (int rr=0; rr<4; ++rr){
        int lr = rt*2 + rr;                // local row 0..11
        const float* rp = &sbuf[cur][lr*200 + 4*cg];
        if (rok[rr]){
          float4 m = *(const float4*)rp;
          vr[rr][0] = xl ? rp[-1] : 0.f;
          vr[rr][1] = m.x; vr[rr][2] = m.y; vr[rr][3] = m.z; vr[rr][4] = m.w;
          vr[rr][5] = xr ? rp[4] : 0.f;
        } else {
          #pragma unroll
          for (int q=0;q<6;++q) vr[rr][q] = 0.f;
        }
      }
      #pragma unroll
      for (int oc=0;oc<3;++oc){
        const float* wp = cw + oc*108 + ci*9;
        float w00=wp[0], w01=wp[1], w02=wp[2],
              w10=wp[3], w11=wp[4], w12=wp[5],
              w20=wp[6], w21=wp[7], w22=wp[8];
        #pragma unroll
        for (int jj=0;jj<2;++jj){
          #pragma unroll
          for (int c=0;c<4;++c){
            float s = acc[oc][jj][c];
            s = fmaf(vr[jj+0][c+0], w00, s); s = fmaf(vr[jj+0][c+1], w01, s); s = fmaf(vr[jj+0][c+2], w02, s);
            s = fmaf(vr[jj+1][c+0], w10, s); s = fmaf(vr[jj+1][c+1], w11, s); s = fmaf(vr[jj+1][c+2], w12, s);
            s = fmaf(vr[jj+2][c+0], w20, s); s = fmaf(vr[jj+2][c+1], w21, s); s = fmaf(vr[jj+2][c+2], w22, s);
            acc[oc][jj][c] = s;
          }
        }
      }
    }
    __syncthreads();                       // buf[cur^1] landed; buf[cur] free for next stage
  }

  if (t < 250){
    float* ob = c1 + (size_t)b*120000;
    int y = y0 + rt*2;
    #pragma unroll
    for (int oc=0;oc<3;++oc)
      #pragma unroll
      for (int jj=0;jj<2;++jj)
        *(float4*)(ob + oc*40000 + (y+jj)*200 + 4*cg) =
          make_float4(acc[oc][jj][0], acc[oc][jj][1], acc[oc][jj][2], acc[oc][jj][3]);
  }
}

// ------------- conv2: 3->32, 3x3, s2, SAME + relu + partial mean. thread = 2 cols x 1 row ------
__global__ __launch_bounds__(256) void k_conv2(const float* __restrict__ c1,
    const float* __restrict__ w2, const float* __restrict__ b2,
    float* __restrict__ part){
  int b = blockIdx.y, ty = blockIdx.x;     // ty 0..19 -> 5 output rows
  int t = threadIdx.x;
  float acc[32];
  #pragma unroll
  for (int co=0;co<32;++co) acc[co]=0.f;
  if (t < 250){
    int oy  = ty*5 + t/50;
    int ox0 = (t%50)*2;
    const float* cbs = c1 + (size_t)b*120000;
    bool xl = (ox0>0);
    float vr[3][3][5];
    #pragma unroll
    for (int ci=0;ci<3;++ci){
      #pragma unroll
      for (int ky=0;ky<3;++ky){
        int iy = 2*oy + ky - 1;
        bool rok = (iy >= 0);              // iy <= 199 always
        const float* rp = cbs + ci*40000 + iy*200 + 2*ox0;
        float4 m = rok ? *(const float4*)rp : make_float4(0.f,0.f,0.f,0.f);
        vr[ci][ky][0] = (rok && xl) ? rp[-1] : 0.f;
        vr[ci][ky][1] = m.x; vr[ci][ky][2] = m.y; vr[ci][ky][3] = m.z; vr[ci][ky][4] = m.w;
      }
    }
    #pragma unroll
    for (int c=0;c<2;++c){
      #pragma unroll
      for (int co=0;co<32;++co){
        float s = b2[co];
        #pragma unroll
        for (int ci=0;ci<3;++ci)
          #pragma unroll
          for (int ky=0;ky<3;++ky)
            #pragma unroll
            for (int kx=0;kx<3;++kx)
              s = fmaf(vr[ci][ky][2*c+kx], w2[co*27+ci*9+ky*3+kx], s);
        acc[co] += fmaxf(s, 0.f);
      }
    }
  }
  int lane = t&63, wv = t>>6;
  __shared__ float wred[4][32];
  #pragma unroll
  for (int co=0;co<32;++co){
    float s = acc[co];
    #pragma unroll
    for (int off=32; off; off>>=1) s += __shfl_down(s, off, 64);
    if (lane==0) wred[wv][co] = s;
  }
  __syncthreads();
  if (t < 32){
    float s = wred[0][t]+wred[1][t]+wred[2][t]+wred[3][t];
    part[(b*20+ty)*32 + t] = s;
  }
}

// ------------- LSTM with inline fc (const4) prologue; 1 block per batch -------------
__global__ __launch_bounds__(256) void k_lstm(
    const float* __restrict__ hist_pts, const float* __restrict__ hist_step,
    const float* __restrict__ emb_w, const float* __restrict__ emb_b,
    const float* __restrict__ h0, const float* __restrict__ c0,
    const float* __restrict__ w_ih, const float* __restrict__ w_hh,
    const float* __restrict__ b_ih, const float* __restrict__ b_hh,
    const float* __restrict__ out_w, const float* __restrict__ out_b,
    const float* __restrict__ part, const float* __restrict__ fcw,
    const float* __restrict__ fcb, float* __restrict__ traj){
  int b = blockIdx.x; int t = threadIdx.x; int lane = t&63, wv = t>>6;

  // ---- inline fc: const4 = (mean-pooled z @ fcw^T + fcb) @ out_w[:,128:]^T + out_b ----
  __shared__ float zfc[32];
  __shared__ float wredfc[4][4];
  if (t < 32){
    float s = 0.f;
    #pragma unroll
    for (int p=0;p<20;++p) s += part[(b*20+p)*32 + t];
    zfc[t] = s * (1.f/10000.f);
  }
  __syncthreads();
  {
    float cp0=0.f, cp1=0.f, cp2=0.f, cp3=0.f;
    for (int o = t; o < 1000; o += 256){
      float s = fcb[o];
      #pragma unroll
      for (int k=0;k<32;++k) s = fmaf(fcw[o*32+k], zfc[k], s);
      cp0 = fmaf(s, out_w[0*1128+128+o], cp0);
      cp1 = fmaf(s, out_w[1*1128+128+o], cp1);
      cp2 = fmaf(s, out_w[2*1128+128+o], cp2);
      cp3 = fmaf(s, out_w[3*1128+128+o], cp3);
    }
    #pragma unroll
    for (int off=32; off; off>>=1){
      cp0 += __shfl_down(cp0, off, 64);
      cp1 += __shfl_down(cp1, off, 64);
      cp2 += __shfl_down(cp2, off, 64);
      cp3 += __shfl_down(cp3, off, 64);
    }
    if (lane==0){ wredfc[wv][0]=cp0; wredfc[wv][1]=cp1; wredfc[wv][2]=cp2; wredfc[wv][3]=cp3; }
  }
  __syncthreads();
  float cst = 0.f;
  if (t < 4) cst = out_b[t] + wredfc[0][t]+wredfc[1][t]+wredfc[2][t]+wredfc[3][t];

  // ---- LSTM ----
  int u  = (t<128) ? t       : t-128;
  int j1 = (t<128) ? t       : 128+u;   // i_u  or f_u
  int j2 = (t<128) ? 256+t   : 384+u;   // g_u  or o_u

  f16x2 w1[96], w2[96];
  {
    const float2* r1 = (const float2*)(w_ih + j1*64);
    const float2* r2 = (const float2*)(w_ih + j2*64);
    #pragma unroll
    for (int p=0;p<32;++p){
      float2 a = r1[p], c = r2[p];
      w1[p] = f16x2{(f16)a.x, (f16)a.y};
      w2[p] = f16x2{(f16)c.x, (f16)c.y};
    }
    const float2* q1 = (const float2*)(w_hh + j1*128);
    const float2* q2 = (const float2*)(w_hh + j2*128);
    #pragma unroll
    for (int p=0;p<64;++p){
      float2 a = q1[p], c = q2[p];
      w1[32+p] = f16x2{(f16)a.x, (f16)a.y};
      w2[32+p] = f16x2{(f16)c.x, (f16)c.y};
    }
  }
  float bias1 = b_ih[j1] + b_hh[j1];
  float bias2 = b_ih[j2] + b_hh[j2];

  __shared__ f16x2 xl[96];
  __shared__ float e_lds[64], h_lds[128], a_lds[128];
  __shared__ float step_lds[4], wred4[4];

  float c_reg = (t>=128) ? c0[u] : 0.f;
  if (t < 128) h_lds[t] = h0[t];

  auto cell = [&](){
    __syncthreads();
    if (t < 32)      xl[t]    = f16x2{(f16)e_lds[2*t],        (f16)e_lds[2*t+1]};
    else if (t < 96){ int p=t-32; xl[t] = f16x2{(f16)h_lds[2*p], (f16)h_lds[2*p+1]}; }
    __syncthreads();
    float acc1 = bias1, acc2 = bias2;
    #pragma unroll
    for (int cc=0; cc<12; ++cc){
      f16x2 xv[8];
      #pragma unroll
      for (int q=0;q<8;++q) xv[q] = xl[cc*8+q];
      #pragma unroll
      for (int q=0;q<8;++q){
        acc1 = dot2acc(w1[cc*8+q], xv[q], acc1);
        acc2 = dot2acc(w2[cc*8+q], xv[q], acc2);
      }
    }
    if (t < 128){
      float ig = 1.f/(1.f+expf(-acc1));
      float gg = tanhf(acc2);
      a_lds[t] = ig*gg;
    }
    __syncthreads();
    if (t >= 128){
      float ff = 1.f/(1.f+expf(-acc1));
      float oo = 1.f/(1.f+expf(-acc2));
      c_reg = ff*c_reg + a_lds[u];
      h_lds[u] = oo * tanhf(c_reg);
    }
  };

  for (int s=1; s<10; ++s){
    if (t < 64){
      const float* hp = hist_step + (size_t)(b*10+s)*4;
      float e = emb_b[t]
              + emb_w[t*4+0]*hp[0] + emb_w[t*4+1]*hp[1]
              + emb_w[t*4+2]*hp[2] + emb_w[t*4+3]*hp[3];
      e_lds[t] = fmaxf(e, 0.f);
    }
    cell();
  }

  float pose = (t<4) ? hist_pts[(size_t)(b*10+9)*4 + t] : 0.f;
  for (int it=0; it<10; ++it){
    __syncthreads();
    {
      const float* owr = out_w + wv*1128;
      float p_ = owr[2*lane]*h_lds[2*lane] + owr[2*lane+1]*h_lds[2*lane+1];
      #pragma unroll
      for (int off=32; off; off>>=1) p_ += __shfl_down(p_, off, 64);
      if (lane==0) wred4[wv] = p_;
    }
    __syncthreads();
    if (t < 4){
      float st = wred4[t] + cst;
      pose += st;
      traj[(size_t)(b*10+it)*4 + t] = pose;
      step_lds[t] = st;
    }
    __syncthreads();
    if (it < 9){
      if (t < 64){
        float e = emb_b[t]
                + emb_w[t*4+0]*step_lds[0] + emb_w[t*4+1]*step_lds[1]
                + emb_w[t*4+2]*step_lds[2] + emb_w[t*4+3]*step_lds[3];
        e_lds[t] = fmaxf(e, 0.f);
      }
      cell();
    }
  }
}

// ------------- rasterizer: max of 3 isotropic gaussians = exp(-min d^2 / (2 s^2)) -------------
__global__ __launch_bounds__(256) void k_raster(const float* __restrict__ traj,
    const float* __restrict__ ego, float* __restrict__ boxes){
  int img = blockIdx.y;
  int b = img / 10;
  __shared__ float ctr[6];
  if (threadIdx.x == 0){
    float x  = traj[img*4+0];
    float y  = traj[img*4+1];
    float hd = traj[img*4+2];
    float eg = ego[b];
    float ho = 1.5707963267948966f - eg;
    float sho, cho; __sincosf(ho, &sho, &cho);
    float pxc = 100.f + (x*cho - y*sho)*10.f;
    float pyc = 160.f - (x*sho + y*cho)*10.f;
    float bh  = -hd - eg;
    float sbh, cbh; __sincosf(bh, &sbh, &cbh);
    const float CSH = 14.235f;
    const float FSH = 28.47f;
    ctr[0] = pxc;             ctr[1] = pyc;
    ctr[2] = pxc + CSH*cbh;   ctr[3] = pyc - CSH*sbh;
    ctr[4] = pxc + FSH*cbh;   ctr[5] = pyc - FSH*sbh;
  }
  __syncthreads();
  int f4 = blockIdx.x*256 + threadIdx.x;
  if (f4 >= 10000) return;
  int p0 = f4*4;
  int i = p0 / 200;
  int j = p0 % 200;
  float fi = (float)i, fj = (float)j;
  float c0x=ctr[0], c0y=ctr[1], c1x=ctr[2], c1y=ctr[3], c2x=ctr[4], c2y=ctr[5];
  float dx0 = fi-c0x, dx1 = fi-c1x, dx2 = fi-c2x;
  float A0 = dx0*dx0, A1 = dx1*dx1, A2 = dx2*dx2;
  const float GA = 0.15432098765432098f;
  float r[4];
  #pragma unroll
  for (int l=0;l<4;++l){
    float dj = fj + (float)l;
    float dy0 = dj-c0y, dy1 = dj-c1y, dy2 = dj-c2y;
    float d0 = fmaf(dy0,dy0,A0);
    float d1 = fmaf(dy1,dy1,A1);
    float d2 = fmaf(dy2,dy2,A2);
    float m = fminf(d0, fminf(d1,d2));
    r[l] = __expf(-m*GA);
  }
  *(float4*)(boxes + (size_t)img*40000 + p0) = make_float4(r[0],r[1],r[2],r[3]);
}

extern "C" void kernel_launch(void* const* d_in, const int* in_sizes, int n_in,
                              void* d_out, int out_size, void* d_ws, size_t ws_size,
                              hipStream_t stream) {
  (void)in_sizes; (void)n_in; (void)d_ws; (void)ws_size; (void)out_size;
  const float* img = (const float*)d_in[0];
  const float* hp  = (const float*)d_in[1];
  const float* hps = (const float*)d_in[2];
  const float* ego = (const float*)d_in[3];
  const float* cw  = (const float*)d_in[4];
  const float* cb  = (const float*)d_in[5];
  const float* c2w = (const float*)d_in[6];
  const float* c2b = (const float*)d_in[7];
  const float* fcw = (const float*)d_in[8];
  const float* fcb = (const float*)d_in[9];
  const float* ew  = (const float*)d_in[10];
  const float* eb  = (const float*)d_in[11];
  const float* h0  = (const float*)d_in[12];
  const float* c0  = (const float*)d_in[13];
  const float* wih = (const float*)d_in[14];
  const float* whh = (const float*)d_in[15];
  const float* bih = (const float*)d_in[16];
  const float* bhh = (const float*)d_in[17];
  const float* ow  = (const float*)d_in[18];
  const float* ob  = (const float*)d_in[19];

  float* out  = (float*)d_out;
  float* traj = out;                 // (64,10,4)
  float* S    = out + 2560;          // boxes region doubles as scratch until k_raster
  float* part = S;                   // 64*20*32 floats
  float* c1   = S + 50000;           // 64*3*200*200 = 7.68M floats (16B-aligned)

  hipLaunchKernelGGL(k_conv1, dim3(20, 64), dim3(256), 0, stream, img, cw, cb, c1);
  hipLaunchKernelGGL(k_conv2, dim3(20, 64), dim3(256), 0, stream, c1, c2w, c2b, part);
  hipLaunchKernelGGL(k_lstm,  dim3(64),     dim3(256), 0, stream,
                     hp, hps, ew, eb, h0, c0, wih, whh, bih, bhh, ow, ob, part, fcw, fcb, traj);
  hipLaunchKernelGGL(k_raster, dim3(40, 640), dim3(256), 0, stream, traj, ego, S);
}